// Round 4
// baseline (27654.056 us; speedup 1.0000x reference)
//
#include <hip/hip_runtime.h>
#include <math.h>

#define B    32
#define EMBD 1024
#define HID  1024
#define G    4096   // 4*HID
#define V    32000
#define TS   128
#define XROW (TS + 1)
#define KSL  32     // gate k-splits over concatenated K=2048 (chunk 64)
#define KSF  4      // fc k-splits over K=1024 (chunk 256)
#define JBF  125    // fc j-blocks (125*256 = 32000)

#define FMA4(acc, W_, V_) \
  acc = fmaf((W_).x,(V_).x, fmaf((W_).y,(V_).y, fmaf((W_).z,(V_).z, fmaf((W_).w,(V_).w,(acc)))))

// ---------------- init: h=c=0, xcur = emb[x[:,0]] ----------------
// grid B, block 256
__global__ __launch_bounds__(256) void k_init(
    const int* __restrict__ x, const float* __restrict__ emb,
    float* __restrict__ xcur, float* __restrict__ h, float* __restrict__ c)
{
    const int b = blockIdx.x, tid = threadIdx.x;
    float4 z = {0.f, 0.f, 0.f, 0.f};
    ((float4*)(h + (size_t)b * HID))[tid] = z;
    ((float4*)(h + (size_t)(B + b) * HID))[tid] = z;
    ((float4*)(c + (size_t)b * HID))[tid] = z;
    ((float4*)(c + (size_t)(B + b) * HID))[tid] = z;
    const int tok = x[b * XROW];
    ((float4*)(xcur + (size_t)b * EMBD))[tid] =
        ((const float4*)(emb + (size_t)tok * EMBD))[tid];
}

// ---------------- LSTM gates partial GEMM (scalar-broadcast x) ----------------
// grid (16 jb, KSL ks), block 256. Thread: 1 j, 64 k (of 2048 concat), 32 b.
// gpart[ks][b][j] += chunk contribution.
__global__ __launch_bounds__(256) void k_gates(
    const float* __restrict__ xa,     // x operand rows [B][1024]
    const float* __restrict__ ha,     // h operand rows [B][1024]
    const float* __restrict__ Wih, const float* __restrict__ Whh,
    float* __restrict__ gpart)
{
    const int tid = threadIdx.x;
    const int j   = blockIdx.x * 256 + tid;     // 0..4095
    const int ks  = blockIdx.y;                 // 0..31
    const int kbase2 = ks * 64;                 // concat-k space
    const bool hpart = (kbase2 >= 1024);
    const float* __restrict__ src = hpart ? ha : xa;
    const float* __restrict__ Wb  = hpart ? Whh : Wih;
    const int kb = kbase2 & 1023;

    const float* wr = Wb + (size_t)j * 1024 + kb;
    float4 w[16];
#pragma unroll
    for (int kk = 0; kk < 16; kk++) w[kk] = *(const float4*)(wr + kk * 4);

    float acc[B];
#pragma unroll
    for (int b = 0; b < B; b++) acc[b] = 0.f;

#pragma unroll
    for (int g = 0; g < 4; g++) {
#pragma unroll
        for (int b = 0; b < B; b++) {
            const float* xb = src + (size_t)b * 1024 + kb + g * 16;  // uniform
            const float4 x0 = *(const float4*)(xb + 0);
            const float4 x1 = *(const float4*)(xb + 4);
            const float4 x2 = *(const float4*)(xb + 8);
            const float4 x3 = *(const float4*)(xb + 12);
            FMA4(acc[b], w[g * 4 + 0], x0);
            FMA4(acc[b], w[g * 4 + 1], x1);
            FMA4(acc[b], w[g * 4 + 2], x2);
            FMA4(acc[b], w[g * 4 + 3], x3);
        }
    }
#pragma unroll
    for (int b = 0; b < B; b++)
        gpart[((size_t)ks * B + b) * G + j] = acc[b];
}

// ---------------- reduce gate partials + activations + state ----------------
// grid 256, block 128; idx = b*1024 + jh
__global__ __launch_bounds__(128) void k_act(
    const float* __restrict__ part, const float* __restrict__ bih,
    const float* __restrict__ bhh, float* __restrict__ c, float* __restrict__ h)
{
    const int idx = blockIdx.x * 128 + threadIdx.x;
    const int b = idx >> 10, jh = idx & 1023;
    float gi = bih[jh]        + bhh[jh];
    float gf = bih[jh + 1024] + bhh[jh + 1024];
    float gg = bih[jh + 2048] + bhh[jh + 2048];
    float go = bih[jh + 3072] + bhh[jh + 3072];
#pragma unroll
    for (int ks = 0; ks < KSL; ks++) {
        const float* p = part + ((size_t)ks * B + b) * G;
        gi += p[jh]; gf += p[jh + 1024]; gg += p[jh + 2048]; go += p[jh + 3072];
    }
    const float i = 1.f / (1.f + expf(-gi));
    const float f = 1.f / (1.f + expf(-gf));
    const float g = tanhf(gg);
    const float o = 1.f / (1.f + expf(-go));
    const float cn = f * c[idx] + i * g;
    c[idx] = cn;
    h[idx] = o * tanhf(cn);
}

// ---------------- FC partial GEMM (scalar-broadcast x) ----------------
// grid (125 jb, KSF ks), block 256. Thread: 1 j, 256 k, 32 b.
__global__ __launch_bounds__(256) void k_fc(
    const float* __restrict__ h1, const float* __restrict__ W,
    float* __restrict__ fpart)
{
    const int tid = threadIdx.x;
    const int j   = blockIdx.x * 256 + tid;     // < 32000
    const int ks  = blockIdx.y;                 // 0..3
    const int kbase = ks * 256;
    const float* wr = W + (size_t)j * HID + kbase;

    float acc[B];
#pragma unroll
    for (int b = 0; b < B; b++) acc[b] = 0.f;

    for (int g = 0; g < 16; g++) {
        const float4 w0 = *(const float4*)(wr + g * 16 + 0);
        const float4 w1 = *(const float4*)(wr + g * 16 + 4);
        const float4 w2 = *(const float4*)(wr + g * 16 + 8);
        const float4 w3 = *(const float4*)(wr + g * 16 + 12);
#pragma unroll
        for (int b = 0; b < B; b++) {
            const float* xb = h1 + (size_t)b * HID + kbase + g * 16;  // uniform
            const float4 x0 = *(const float4*)(xb + 0);
            const float4 x1 = *(const float4*)(xb + 4);
            const float4 x2 = *(const float4*)(xb + 8);
            const float4 x3 = *(const float4*)(xb + 12);
            FMA4(acc[b], w0, x0);
            FMA4(acc[b], w1, x1);
            FMA4(acc[b], w2, x2);
            FMA4(acc[b], w3, x3);
        }
    }
#pragma unroll
    for (int b = 0; b < B; b++)
        fpart[((size_t)ks * B + b) * V + j] = acc[b];
}

// ---------------- FC reduce + exp/max/argmax partials ----------------
// grid (125 jb, 32 b), block 256
__global__ __launch_bounds__(256) void k_fcsm(
    const float* __restrict__ fpart, const float* __restrict__ bfc,
    const int* __restrict__ x, int t,
    float* __restrict__ psum, float* __restrict__ pmax, int* __restrict__ pidx,
    float* __restrict__ lt)
{
    const int jb = blockIdx.x;   // 0..124
    const int b  = blockIdx.y;   // 0..31
    const int tid = threadIdx.x;
    const int j = jb * 256 + tid;
    float l = bfc[j];
#pragma unroll
    for (int ks = 0; ks < KSF; ks++)
        l += fpart[((size_t)ks * B + b) * V + j];
    const int tgt = x[b * XROW + t + 1];
    if (j == tgt) lt[b] = l;

    __shared__ float ss[256], sm[256];
    __shared__ int si[256];
    ss[tid] = expf(l); sm[tid] = l; si[tid] = j;
    __syncthreads();
    for (int s = 128; s > 0; s >>= 1) {
        if (tid < s) {
            ss[tid] += ss[tid + s];
            const float mv = sm[tid + s]; const int mi = si[tid + s];
            if (mv > sm[tid] || (mv == sm[tid] && mi < si[tid])) {
                sm[tid] = mv; si[tid] = mi;
            }
        }
        __syncthreads();
    }
    if (tid == 0) {
        psum[b * JBF + jb] = ss[0];
        pmax[b * JBF + jb] = sm[0];
        pidx[b * JBF + jb] = si[0];
    }
}

// ---------------- finalize: p(target), argmax -> xcur = emb[pred] ----------------
// grid 32 (b), block 256
__global__ __launch_bounds__(256) void k_fin(
    const float* __restrict__ psum, const float* __restrict__ pmax,
    const int* __restrict__ pidx, const float* __restrict__ lt,
    const float* __restrict__ emb, float* __restrict__ xcur,
    float* __restrict__ out, int t)
{
    const int b = blockIdx.x, tid = threadIdx.x;
    __shared__ float ss[128], sm[128];
    __shared__ int si[128];
    __shared__ int s_pred;
    if (tid < 128) {
        const bool v = (tid < JBF);
        ss[tid] = v ? psum[b * JBF + tid] : 0.f;
        sm[tid] = v ? pmax[b * JBF + tid] : -1e30f;
        si[tid] = v ? pidx[b * JBF + tid] : 0x7fffffff;
    }
    __syncthreads();
    for (int s = 64; s > 0; s >>= 1) {
        if (tid < s) {
            ss[tid] += ss[tid + s];
            const float mv = sm[tid + s]; const int ix = si[tid + s];
            if (mv > sm[tid] || (mv == sm[tid] && ix < si[tid])) {
                sm[tid] = mv; si[tid] = ix;
            }
        }
        __syncthreads();
    }
    if (tid == 0) {
        out[(size_t)b * TS + t] = expf(lt[b]) / ss[0];
        s_pred = si[0];
    }
    __syncthreads();
    ((float4*)(xcur + (size_t)b * EMBD))[tid] =
        ((const float4*)(emb + (size_t)s_pred * EMBD))[tid];
}

extern "C" void kernel_launch(void* const* d_in, const int* in_sizes, int n_in,
                              void* d_out, int out_size, void* d_ws, size_t ws_size,
                              hipStream_t stream)
{
    const int*   x   = (const int*)  d_in[0];
    const float* emb = (const float*)d_in[1];
    const float* Wih = (const float*)d_in[2];
    const float* Whh = (const float*)d_in[3];
    const float* bih = (const float*)d_in[4];
    const float* bhh = (const float*)d_in[5];
    const float* Wfc = (const float*)d_in[6];
    const float* bfc = (const float*)d_in[7];
    float* out = (float*)d_out;

    float* ws = (float*)d_ws;
    float* xcur  = ws;                                  // B*EMBD
    float* h     = xcur + (size_t)B * EMBD;             // 2*B*HID
    float* c     = h + 2 * (size_t)B * HID;             // 2*B*HID
    float* gpart = c + 2 * (size_t)B * HID;             // KSL*B*G
    float* fpart = gpart + (size_t)KSL * B * G;         // KSF*B*V
    float* psum  = fpart + (size_t)KSF * B * V;         // B*JBF
    float* pmax  = psum + B * JBF;                      // B*JBF
    float* lt    = pmax + B * JBF;                      // B
    int*   pidx  = (int*)(lt + B);                      // B*JBF

    float* h0 = h, *h1 = h + (size_t)B * HID;
    float* c0 = c, *c1 = c + (size_t)B * HID;

    k_init<<<B, 256, 0, stream>>>(x, emb, xcur, h, c);

    for (int t = 0; t < TS; t++) {
        // layer 0 (x = xcur)
        k_gates<<<dim3(16, KSL), 256, 0, stream>>>(xcur, h0, Wih, Whh, gpart);
        k_act<<<256, 128, 0, stream>>>(gpart, bih, bhh, c0, h0);
        // layer 1 (x = h0)
        k_gates<<<dim3(16, KSL), 256, 0, stream>>>(h0, h1,
                                                   Wih + (size_t)G * EMBD,
                                                   Whh + (size_t)G * HID, gpart);
        k_act<<<256, 128, 0, stream>>>(gpart, bih + G, bhh + G, c1, h1);
        // FC + softmax partials + finalize (writes xcur for t+1)
        k_fc<<<dim3(JBF, KSF), 256, 0, stream>>>(h1, Wfc, fpart);
        k_fcsm<<<dim3(JBF, B), 256, 0, stream>>>(fpart, bfc, x, t, psum, pmax, pidx, lt);
        k_fin<<<B, 256, 0, stream>>>(psum, pmax, pidx, lt, emb, xcur, out, t);
    }
}

// Round 5
// 16193.317 us; speedup vs baseline: 1.7077x; 1.7077x over previous
//
#include <hip/hip_runtime.h>
#include <math.h>

#define B    32
#define EMBD 1024
#define HID  1024
#define G    4096   // 4*HID
#define V    32000
#define TS   128
#define XROW (TS + 1)
#define KSL  32     // gate k-splits (chunk = 32)
#define KSF  4      // fc block-level k-splits (chunk = 256)
#define JBF  125    // fc j-blocks (125*256 = 32000)

#define FMA4(acc, W_, V_) \
  acc = fmaf((W_).x,(V_).x, fmaf((W_).y,(V_).y, fmaf((W_).z,(V_).z, fmaf((W_).w,(V_).w,(acc)))))

// ---------------- init: h=c=0, xcur = emb[x[:,0]] ----------------
// grid B, block 256
__global__ __launch_bounds__(256) void k_init(
    const int* __restrict__ x, const float* __restrict__ emb,
    float* __restrict__ xcur, float* __restrict__ h, float* __restrict__ c)
{
    const int b = blockIdx.x, tid = threadIdx.x;
    float4 z = {0.f, 0.f, 0.f, 0.f};
    ((float4*)(h + (size_t)b * HID))[tid] = z;
    ((float4*)(h + (size_t)(B + b) * HID))[tid] = z;
    ((float4*)(c + (size_t)b * HID))[tid] = z;
    ((float4*)(c + (size_t)(B + b) * HID))[tid] = z;
    const int tok = x[b * XROW];
    ((float4*)(xcur + (size_t)b * EMBD))[tid] =
        ((const float4*)(emb + (size_t)tok * EMBD))[tid];
}

// ---------------- LSTM gates partial GEMM (R2-proven LDS-staged) ----------------
// grid (8, KSL), block 256. Each thread: 2 j's (tid, tid+256), all 32 b's.
__global__ __launch_bounds__(256) void k_gates(
    const float* __restrict__ xin, const float* __restrict__ hin,
    const float* __restrict__ Wih, const float* __restrict__ Whh,
    float* __restrict__ part)
{
    __shared__ float4 xs[B][8];
    __shared__ float4 hs[B][8];
    const int tid = threadIdx.x;
    const int bj = blockIdx.x;      // 0..7
    const int ks = blockIdx.y;      // 0..KSL-1
    const int kbase = ks * (EMBD / KSL);   // *32
    {
        const int b = tid >> 3, kk = tid & 7;
        xs[b][kk] = *(const float4*)(xin + (size_t)b * EMBD + kbase + kk * 4);
        hs[b][kk] = *(const float4*)(hin + (size_t)b * HID + kbase + kk * 4);
    }
    __syncthreads();

    const int j0 = bj * 512 + tid;
    const int j1 = j0 + 256;
    const float* wi0 = Wih + (size_t)j0 * EMBD + kbase;
    const float* wi1 = Wih + (size_t)j1 * EMBD + kbase;
    const float* wh0 = Whh + (size_t)j0 * HID + kbase;
    const float* wh1 = Whh + (size_t)j1 * HID + kbase;

    float acc0[B], acc1[B];
#pragma unroll
    for (int b = 0; b < B; b++) { acc0[b] = 0.f; acc1[b] = 0.f; }

#pragma unroll 2
    for (int kk = 0; kk < 8; kk++) {
        float4 a0 = *(const float4*)(wi0 + kk * 4);
        float4 a1 = *(const float4*)(wi1 + kk * 4);
        float4 c0 = *(const float4*)(wh0 + kk * 4);
        float4 c1 = *(const float4*)(wh1 + kk * 4);
#pragma unroll
        for (int b = 0; b < B; b++) {
            float4 xv = xs[b][kk];
            float4 hv = hs[b][kk];
            FMA4(acc0[b], a0, xv);
            FMA4(acc0[b], c0, hv);
            FMA4(acc1[b], a1, xv);
            FMA4(acc1[b], c1, hv);
        }
    }
#pragma unroll
    for (int b = 0; b < B; b++) {
        part[((size_t)ks * B + b) * G + j0] = acc0[b];
        part[((size_t)ks * B + b) * G + j1] = acc1[b];
    }
}

// ---------------- reduce gate partials + activations + state ----------------
// grid 128, block 256; idx = b*1024 + jh
__global__ __launch_bounds__(256) void k_act(
    const float* __restrict__ part, const float* __restrict__ bih,
    const float* __restrict__ bhh, float* __restrict__ c, float* __restrict__ h)
{
    const int idx = blockIdx.x * 256 + threadIdx.x;
    const int b = idx >> 10, jh = idx & 1023;
    float gi = bih[jh]        + bhh[jh];
    float gf = bih[jh + 1024] + bhh[jh + 1024];
    float gg = bih[jh + 2048] + bhh[jh + 2048];
    float go = bih[jh + 3072] + bhh[jh + 3072];
#pragma unroll
    for (int ks = 0; ks < KSL; ks++) {
        const float* p = part + ((size_t)ks * B + b) * G;
        gi += p[jh]; gf += p[jh + 1024]; gg += p[jh + 2048]; go += p[jh + 3072];
    }
    const float i = 1.f / (1.f + expf(-gi));
    const float f = 1.f / (1.f + expf(-gf));
    const float g = tanhf(gg);
    const float o = 1.f / (1.f + expf(-go));
    const float cn = f * c[idx] + i * g;
    c[idx] = cn;
    h[idx] = o * tanhf(cn);
}

// ---------------- FC partial GEMM v2 ----------------
// grid (125 jb, 4 ksb), block 256 = 4 ksub-waves x 64 jl.
// Thread: 4 consecutive j rows, 64 k (ksb*256 + ksub*64), all 32 b.
// In-block 4-way ksub reduce -> fpart[ksb][b][j].
__global__ __launch_bounds__(256) void k_fc(
    const float* __restrict__ h1, const float* __restrict__ W,
    float* __restrict__ fpart)
{
    __shared__ float4 smem4[2112];           // 33 KB: xs (2048 f4) then red (8448 f)
    float4* xsv = smem4;                     // [ksub][b][kk] = (ksub*32+b)*16+kk
    float* red  = (float*)smem4;             // [ksub][jl][33] padded

    const int tid  = threadIdx.x;
    const int jl   = tid & 63;
    const int ksub = tid >> 6;               // wave id (uniform per wave)
    const int jb   = blockIdx.x;             // 0..124
    const int ksb  = blockIdx.y;             // 0..3

    // stage h1 chunk [32 b][256 k] into xs
    const float4* h1v = (const float4*)h1;   // [32][256]
#pragma unroll
    for (int i = 0; i < 8; i++) {
        const int l = tid + i * 256;         // 0..2047
        const int b = l >> 6, kf = l & 63;
        const int ks2 = kf >> 4, kk = kf & 15;
        xsv[(ks2 * 32 + b) * 16 + kk] = h1v[b * 256 + ksb * 64 + kf];
    }
    __syncthreads();

    const int j0 = jb * 256 + jl * 4;
    const float4* wv = (const float4*)W;     // [32000][256]
    const size_t wbase = (size_t)j0 * 256 + ksb * 64 + ksub * 16;
    const float4* xbase = xsv + ksub * 32 * 16;

    float acc[4][B];
#pragma unroll
    for (int q = 0; q < 4; q++)
#pragma unroll
        for (int b = 0; b < B; b++) acc[q][b] = 0.f;

#pragma unroll 4
    for (int kk = 0; kk < 16; kk++) {
        const float4 w0 = wv[wbase + 0 * 256 + kk];
        const float4 w1 = wv[wbase + 1 * 256 + kk];
        const float4 w2 = wv[wbase + 2 * 256 + kk];
        const float4 w3 = wv[wbase + 3 * 256 + kk];
#pragma unroll
        for (int b = 0; b < B; b++) {
            const float4 xv = xbase[b * 16 + kk];
            FMA4(acc[0][b], w0, xv);
            FMA4(acc[1][b], w1, xv);
            FMA4(acc[2][b], w2, xv);
            FMA4(acc[3][b], w3, xv);
        }
    }

    // 4-way ksub reduce per q-row, then store
    for (int q = 0; q < 4; q++) {
        __syncthreads();
#pragma unroll
        for (int b = 0; b < B; b++)
            red[(ksub * 64 + jl) * 33 + b] = acc[q][b];
        __syncthreads();
        const int jl2 = tid & 63;
        const int bg  = tid >> 6;
#pragma unroll
        for (int i = 0; i < 8; i++) {
            const int b = bg * 8 + i;
            const float s = red[(0 * 64 + jl2) * 33 + b]
                          + red[(1 * 64 + jl2) * 33 + b]
                          + red[(2 * 64 + jl2) * 33 + b]
                          + red[(3 * 64 + jl2) * 33 + b];
            fpart[((size_t)ksb * B + b) * V + jb * 256 + jl2 * 4 + q] = s;
        }
    }
}

// ---------------- FC reduce + exp/max/argmax partials ----------------
// grid (125 jb, 32 b), block 256
__global__ __launch_bounds__(256) void k_fcsm(
    const float* __restrict__ fpart, const float* __restrict__ bfc,
    const int* __restrict__ x, int t,
    float* __restrict__ psum, float* __restrict__ pmax, int* __restrict__ pidx,
    float* __restrict__ lt)
{
    const int jb = blockIdx.x;   // 0..124
    const int b  = blockIdx.y;   // 0..31
    const int tid = threadIdx.x;
    const int j = jb * 256 + tid;
    float l = bfc[j];
#pragma unroll
    for (int ks = 0; ks < KSF; ks++)
        l += fpart[((size_t)ks * B + b) * V + j];
    const int tgt = x[b * XROW + t + 1];
    if (j == tgt) lt[b] = l;

    __shared__ float ss[256], sm[256];
    __shared__ int si[256];
    ss[tid] = expf(l); sm[tid] = l; si[tid] = j;
    __syncthreads();
    for (int s = 128; s > 0; s >>= 1) {
        if (tid < s) {
            ss[tid] += ss[tid + s];
            const float mv = sm[tid + s]; const int mi = si[tid + s];
            if (mv > sm[tid] || (mv == sm[tid] && mi < si[tid])) {
                sm[tid] = mv; si[tid] = mi;
            }
        }
        __syncthreads();
    }
    if (tid == 0) {
        psum[b * JBF + jb] = ss[0];
        pmax[b * JBF + jb] = sm[0];
        pidx[b * JBF + jb] = si[0];
    }
}

// ---------------- finalize: p(target), argmax -> xcur = emb[pred] ----------------
// grid 32 (b), block 256
__global__ __launch_bounds__(256) void k_fin(
    const float* __restrict__ psum, const float* __restrict__ pmax,
    const int* __restrict__ pidx, const float* __restrict__ lt,
    const float* __restrict__ emb, float* __restrict__ xcur,
    float* __restrict__ out, int t)
{
    const int b = blockIdx.x, tid = threadIdx.x;
    __shared__ float ss[128], sm[128];
    __shared__ int si[128];
    __shared__ int s_pred;
    if (tid < 128) {
        const bool v = (tid < JBF);
        ss[tid] = v ? psum[b * JBF + tid] : 0.f;
        sm[tid] = v ? pmax[b * JBF + tid] : -1e30f;
        si[tid] = v ? pidx[b * JBF + tid] : 0x7fffffff;
    }
    __syncthreads();
    for (int s = 64; s > 0; s >>= 1) {
        if (tid < s) {
            ss[tid] += ss[tid + s];
            const float mv = sm[tid + s]; const int ix = si[tid + s];
            if (mv > sm[tid] || (mv == sm[tid] && ix < si[tid])) {
                sm[tid] = mv; si[tid] = ix;
            }
        }
        __syncthreads();
    }
    if (tid == 0) {
        out[(size_t)b * TS + t] = expf(lt[b]) / ss[0];
        s_pred = si[0];
    }
    __syncthreads();
    ((float4*)(xcur + (size_t)b * EMBD))[tid] =
        ((const float4*)(emb + (size_t)s_pred * EMBD))[tid];
}

extern "C" void kernel_launch(void* const* d_in, const int* in_sizes, int n_in,
                              void* d_out, int out_size, void* d_ws, size_t ws_size,
                              hipStream_t stream)
{
    const int*   x   = (const int*)  d_in[0];
    const float* emb = (const float*)d_in[1];
    const float* Wih = (const float*)d_in[2];
    const float* Whh = (const float*)d_in[3];
    const float* bih = (const float*)d_in[4];
    const float* bhh = (const float*)d_in[5];
    const float* Wfc = (const float*)d_in[6];
    const float* bfc = (const float*)d_in[7];
    float* out = (float*)d_out;

    float* ws = (float*)d_ws;
    float* xcur  = ws;                                  // B*EMBD
    float* h     = xcur + (size_t)B * EMBD;             // 2*B*HID
    float* c     = h + 2 * (size_t)B * HID;             // 2*B*HID
    float* gpart = c + 2 * (size_t)B * HID;             // KSL*B*G
    float* fpart = gpart + (size_t)KSL * B * G;         // KSF*B*V
    float* psum  = fpart + (size_t)KSF * B * V;         // B*JBF
    float* pmax  = psum + B * JBF;                      // B*JBF
    float* lt    = pmax + B * JBF;                      // B
    int*   pidx  = (int*)(lt + B);                      // B*JBF

    float* h0 = h, *h1 = h + (size_t)B * HID;
    float* c0 = c, *c1 = c + (size_t)B * HID;

    k_init<<<B, 256, 0, stream>>>(x, emb, xcur, h, c);

    for (int t = 0; t < TS; t++) {
        // layer 0
        k_gates<<<dim3(8, KSL), 256, 0, stream>>>(xcur, h0, Wih, Whh, gpart);
        k_act<<<128, 256, 0, stream>>>(gpart, bih, bhh, c0, h0);
        // layer 1
        k_gates<<<dim3(8, KSL), 256, 0, stream>>>(h0, h1,
                                                  Wih + (size_t)G * EMBD,
                                                  Whh + (size_t)G * HID, gpart);
        k_act<<<128, 256, 0, stream>>>(gpart, bih + G, bhh + G, c1, h1);
        // FC + softmax partials + finalize (writes xcur for t+1)
        k_fc<<<dim3(JBF, KSF), 256, 0, stream>>>(h1, Wfc, fpart);
        k_fcsm<<<dim3(JBF, B), 256, 0, stream>>>(fpart, bfc, x, t, psum, pmax, pidx, lt);
        k_fin<<<B, 256, 0, stream>>>(psum, pmax, pidx, lt, emb, xcur, out, t);
    }
}